// Round 1
// baseline (234.822 us; speedup 1.0000x reference)
//
#include <hip/hip_runtime.h>

#define MARGIN_NEG 0.4f
#define MARGIN_POS 0.01f

// Problem constants (fixed by the reference):
// B=64, C=3, H=W=256  -> N = 12,582,912 elements per image tensor
// z: B=64, D = 64*16*16 = 16384
#define N_ELEM   12582912
#define N4       (N_ELEM / 4)
#define BATCH    64
#define DIMZ     16384

// ws layout (doubles): [0] = sum of sq diffs (both pairs), [1] = lossP sum, [2] = lossN sum

__global__ void mse_kernel(const float4* __restrict__ o1, const float4* __restrict__ i1,
                           const float4* __restrict__ o2, const float4* __restrict__ i2,
                           double* __restrict__ ws) {
    int tid = blockIdx.x * blockDim.x + threadIdx.x;
    int stride = gridDim.x * blockDim.x;
    float acc = 0.f;
    for (int i = tid; i < N4; i += stride) {
        float4 a = o1[i], b = i1[i];
        float dx = a.x - b.x, dy = a.y - b.y, dz = a.z - b.z, dw = a.w - b.w;
        acc += dx * dx + dy * dy + dz * dz + dw * dw;
        float4 c = o2[i], d = i2[i];
        dx = c.x - d.x; dy = c.y - d.y; dz = c.z - d.z; dw = c.w - d.w;
        acc += dx * dx + dy * dy + dz * dz + dw * dw;
    }
    // wave (64-lane) reduction
    #pragma unroll
    for (int off = 32; off > 0; off >>= 1) acc += __shfl_down(acc, off, 64);
    __shared__ float warp_sums[4];
    int lane = threadIdx.x & 63, wid = threadIdx.x >> 6;
    if (lane == 0) warp_sums[wid] = acc;
    __syncthreads();
    if (threadIdx.x == 0) {
        float s = warp_sums[0] + warp_sums[1] + warp_sums[2] + warp_sums[3];
        atomicAdd(ws, (double)s);
    }
}

// 4x4 (m,n) pair tile per block; 16x16 = 256 blocks cover the 64x64 pair matrix.
__global__ void contrastive_kernel(const float* __restrict__ z1, const float* __restrict__ z2,
                                   double* __restrict__ ws) {
    const int TM = 4, TN = 4;
    int m0 = (blockIdx.x >> 4) * TM;
    int n0 = (blockIdx.x & 15) * TN;
    int t = threadIdx.x;                 // 256 threads
    int lane = t & 63, wid = t >> 6;

    float acc[16];
    #pragma unroll
    for (int p = 0; p < 16; p++) acc[p] = 0.f;

    // D/4 = 4096 float4 chunks, 256 threads -> 16 chunks per thread
    const float4* z1v = (const float4*)z1;
    const float4* z2v = (const float4*)z2;
    const int row4 = DIMZ / 4;
    for (int c = t; c < row4; c += 256) {
        float4 a[TM], b[TN];
        #pragma unroll
        for (int i = 0; i < TM; i++) a[i] = z1v[(m0 + i) * row4 + c];
        #pragma unroll
        for (int j = 0; j < TN; j++) b[j] = z2v[(n0 + j) * row4 + c];
        #pragma unroll
        for (int i = 0; i < TM; i++) {
            #pragma unroll
            for (int j = 0; j < TN; j++) {
                float dx = a[i].x - b[j].x, dy = a[i].y - b[j].y;
                float dz = a[i].z - b[j].z, dw = a[i].w - b[j].w;
                acc[i * TN + j] += dx * dx + dy * dy + dz * dz + dw * dw;
            }
        }
    }

    __shared__ float wsum[4][16];
    #pragma unroll
    for (int p = 0; p < 16; p++) {
        float v = acc[p];
        #pragma unroll
        for (int off = 32; off > 0; off >>= 1) v += __shfl_down(v, off, 64);
        if (lane == 0) wsum[wid][p] = v;
    }
    __syncthreads();

    if (t < 16) {
        float s = wsum[0][t] + wsum[1][t] + wsum[2][t] + wsum[3][t];
        float d = s * (1.0f / (float)DIMZ);
        int m = m0 + (t >> 2), n = n0 + (t & 3);
        float p = 0.f, q = 0.f;
        if (m == n) {
            if (d > MARGIN_POS) p = d - MARGIN_POS;
        } else {
            if (d < MARGIN_NEG) q = MARGIN_NEG - d;
        }
        // threads 0..15 are in wave 0; reduce their p/q
        #pragma unroll
        for (int off = 8; off > 0; off >>= 1) {
            p += __shfl_down(p, off, 64);
            q += __shfl_down(q, off, 64);
        }
        if (t == 0) {
            if (p != 0.f) atomicAdd(ws + 1, (double)p);
            if (q != 0.f) atomicAdd(ws + 2, (double)q);
        }
    }
}

__global__ void finalize_kernel(const double* __restrict__ ws, float* __restrict__ out) {
    double recon = ws[0] / (double)N_ELEM;
    double lossP = ws[1] / (double)BATCH;
    double lossN = ws[2] / ((double)BATCH * (double)(BATCH - 1));
    out[0] = (float)(recon + 1.5 * lossP + 0.5 * lossN);
}

extern "C" void kernel_launch(void* const* d_in, const int* in_sizes, int n_in,
                              void* d_out, int out_size, void* d_ws, size_t ws_size,
                              hipStream_t stream) {
    const float* outputs1 = (const float*)d_in[0];
    const float* z1       = (const float*)d_in[1];
    const float* outputs2 = (const float*)d_in[2];
    const float* z2       = (const float*)d_in[3];
    const float* input1   = (const float*)d_in[4];
    const float* input2   = (const float*)d_in[5];
    float* out = (float*)d_out;
    double* ws = (double*)d_ws;

    hipMemsetAsync(ws, 0, 3 * sizeof(double), stream);

    mse_kernel<<<2048, 256, 0, stream>>>((const float4*)outputs1, (const float4*)input1,
                                         (const float4*)outputs2, (const float4*)input2, ws);
    contrastive_kernel<<<256, 256, 0, stream>>>(z1, z2, ws);
    finalize_kernel<<<1, 1, 0, stream>>>(ws, out);
}

// Round 2
// 222.795 us; speedup vs baseline: 1.0540x; 1.0540x over previous
//
#include <hip/hip_runtime.h>

#define MARGIN_NEG 0.4f
#define MARGIN_POS 0.01f

// Problem constants (fixed by the reference):
// B=64, C=3, H=W=256 -> N = 12,582,912 elems per image tensor; z: 64 x 16384
#define N_ELEM   12582912
#define N4       (N_ELEM / 4)      // 3145728 float4 per tensor
#define BATCH    64
#define DIMZ     16384
#define ROW4     (DIMZ / 4)        // 4096 float4 per z-row

// Grid layout for fused kernel 1 (256 threads/block):
//   blocks [0, CB)                : contrastive partial-d  (k-split x4)
//   blocks [CB, CB+MBP)           : MSE pair 1 (outputs1 - input1)
//   blocks [CB+MBP, CB+2*MBP)     : MSE pair 2 (outputs2 - input2)
#define CB   1024
#define MBP  2048
#define TPP  (MBP * 256)           // 524288 threads per MSE pair
#define MSE_ITERS (N4 / TPP)       // exactly 6 (compile-time!)

// ws layout (floats): [0..4095] = d[m][n] partial sums; [4160] = MSE sq-diff sum
#define WS_MSE_IDX 4160
#define WS_FLOATS  4161

__global__ __launch_bounds__(256) void fused_pass1(
        const float* __restrict__ o1, const float* __restrict__ i1,
        const float* __restrict__ o2, const float* __restrict__ i2,
        const float* __restrict__ z1, const float* __restrict__ z2,
        float* __restrict__ ws) {
    const int b = blockIdx.x;
    const int t = threadIdx.x;
    const int lane = t & 63, wid = t >> 6;

    if (b < CB) {
        // ---- contrastive pass 1: partial sums of sum_k (z1[m,k]-z2[n,k])^2 ----
        // 4 k-chunks x 256 pair-tiles; tile = 4x4 (m,n) pairs
        const int kc   = b & 3;            // k-chunk: 1024 float4 = 4096 floats
        const int tile = b >> 2;           // 0..255
        const int m0 = (tile >> 4) * 4;
        const int n0 = (tile & 15) * 4;
        const float4* z1v = (const float4*)z1;
        const float4* z2v = (const float4*)z2;

        float acc[16];
        #pragma unroll
        for (int p = 0; p < 16; p++) acc[p] = 0.f;

        const int cbase = kc * 1024 + t;
        #pragma unroll
        for (int it = 0; it < 4; it++) {
            const int c = cbase + it * 256;
            float4 a[4], bb[4];
            #pragma unroll
            for (int i = 0; i < 4; i++) a[i] = z1v[(m0 + i) * ROW4 + c];
            #pragma unroll
            for (int j = 0; j < 4; j++) bb[j] = z2v[(n0 + j) * ROW4 + c];
            #pragma unroll
            for (int i = 0; i < 4; i++) {
                #pragma unroll
                for (int j = 0; j < 4; j++) {
                    float dx = a[i].x - bb[j].x, dy = a[i].y - bb[j].y;
                    float dz = a[i].z - bb[j].z, dw = a[i].w - bb[j].w;
                    acc[i * 4 + j] += dx * dx + dy * dy + dz * dz + dw * dw;
                }
            }
        }

        __shared__ float wsum[4][16];
        #pragma unroll
        for (int p = 0; p < 16; p++) {
            float v = acc[p];
            #pragma unroll
            for (int off = 32; off > 0; off >>= 1) v += __shfl_down(v, off, 64);
            if (lane == 0) wsum[wid][p] = v;
        }
        __syncthreads();
        if (t < 16) {
            float s = wsum[0][t] + wsum[1][t] + wsum[2][t] + wsum[3][t];
            int m = m0 + (t >> 2), n = n0 + (t & 3);
            atomicAdd(&ws[m * 64 + n], s);
        }
    } else {
        // ---- MSE: fully unrolled, compile-time trip count, 12 loads in flight ----
        int mb = b - CB;
        const float4 *A, *Bv;
        if (mb < MBP) { A = (const float4*)o1; Bv = (const float4*)i1; }
        else          { A = (const float4*)o2; Bv = (const float4*)i2; mb -= MBP; }
        const int tid = mb * 256 + t;

        float acc0 = 0.f, acc1 = 0.f;
        #pragma unroll
        for (int s = 0; s < MSE_ITERS; s += 2) {
            float4 x0 = A[tid + s * TPP],       y0 = Bv[tid + s * TPP];
            float4 x1 = A[tid + (s + 1) * TPP], y1 = Bv[tid + (s + 1) * TPP];
            float a0 = x0.x - y0.x, a1 = x0.y - y0.y, a2 = x0.z - y0.z, a3 = x0.w - y0.w;
            acc0 += a0 * a0 + a1 * a1 + a2 * a2 + a3 * a3;
            float b0 = x1.x - y1.x, b1 = x1.y - y1.y, b2 = x1.z - y1.z, b3 = x1.w - y1.w;
            acc1 += b0 * b0 + b1 * b1 + b2 * b2 + b3 * b3;
        }
        float v = acc0 + acc1;
        #pragma unroll
        for (int off = 32; off > 0; off >>= 1) v += __shfl_down(v, off, 64);
        __shared__ float ws4[4];
        if (lane == 0) ws4[wid] = v;
        __syncthreads();
        if (t == 0) atomicAdd(&ws[WS_MSE_IDX], ws4[0] + ws4[1] + ws4[2] + ws4[3]);
    }
}

// Margin pass + finalize: one block of 256 threads over the 64x64 d matrix.
__global__ __launch_bounds__(256) void fused_pass2(const float* __restrict__ ws,
                                                   float* __restrict__ out) {
    const int t = threadIdx.x;
    const int lane = t & 63, wid = t >> 6;
    float p = 0.f, q = 0.f;
    #pragma unroll
    for (int s = 0; s < 16; s++) {
        int idx = t + s * 256;
        float d = ws[idx] * (1.0f / (float)DIMZ);
        int m = idx >> 6, n = idx & 63;
        if (m == n) { if (d > MARGIN_POS) p += d - MARGIN_POS; }
        else        { if (d < MARGIN_NEG) q += MARGIN_NEG - d; }
    }
    #pragma unroll
    for (int off = 32; off > 0; off >>= 1) {
        p += __shfl_down(p, off, 64);
        q += __shfl_down(q, off, 64);
    }
    __shared__ float sp[4], sq[4];
    if (lane == 0) { sp[wid] = p; sq[wid] = q; }
    __syncthreads();
    if (t == 0) {
        float P = sp[0] + sp[1] + sp[2] + sp[3];
        float Q = sq[0] + sq[1] + sq[2] + sq[3];
        float recon = ws[WS_MSE_IDX] * (1.0f / (float)N_ELEM);
        out[0] = recon + 1.5f * (P / (float)BATCH)
                       + 0.5f * (Q / (float)(BATCH * (BATCH - 1)));
    }
}

extern "C" void kernel_launch(void* const* d_in, const int* in_sizes, int n_in,
                              void* d_out, int out_size, void* d_ws, size_t ws_size,
                              hipStream_t stream) {
    const float* outputs1 = (const float*)d_in[0];
    const float* z1       = (const float*)d_in[1];
    const float* outputs2 = (const float*)d_in[2];
    const float* z2       = (const float*)d_in[3];
    const float* input1   = (const float*)d_in[4];
    const float* input2   = (const float*)d_in[5];
    float* out = (float*)d_out;
    float* ws  = (float*)d_ws;

    hipMemsetAsync(ws, 0, WS_FLOATS * sizeof(float), stream);

    fused_pass1<<<CB + 2 * MBP, 256, 0, stream>>>(outputs1, input1, outputs2, input2,
                                                  z1, z2, ws);
    fused_pass2<<<1, 256, 0, stream>>>(ws, out);
}